// Round 5
// baseline (560.142 us; speedup 1.0000x reference)
//
#include <hip/hip_runtime.h>

#define TT   512
#define DD   6
#define HD   32
#define CH   32          // x-staging chunk (timesteps)
#define EPSL 1e-5f

typedef _Float16 half8 __attribute__((ext_vector_type(8)));
typedef __attribute__((ext_vector_type(4))) float f32x4;

#define MFMA_F16(a, b, c) __builtin_amdgcn_mfma_f32_16x16x32_f16((a), (b), (c), 0, 0, 0)

// ====================================================================
// R5: all sigmoid/tanh -> 1024-entry LDS table + lerp.
// R4 counters: VALUBusy 52% of 1647cy/iter = 856 VALU-cy; only consistent
// with v_exp/v_rcp at ~16cy/wave64 -> the 40 trans ops/wave/iter (~640cy)
// dominate issue. Table eval = ~7 full-rate VALU + 1 ds_read_b64 (~14cy),
// moving the work to the near-idle LDS pipe. tanh(z)=2*sig(2z)-1 with the
// 2x folded into the index fma (free).
// sig table: x in [-16,16), step 1/32: entry i = (sig(x0), sig(x0+d)-sig(x0)).
// lerp err <= 1.2e-5, clamp err <= 1.1e-7 (<< fp16 MFMA noise).
// ====================================================================
__global__ __launch_bounds__(256, 1) void lstm2_pipe(
    const float* __restrict__ x,      // (B,512,6)
    const float* __restrict__ W_ih0,  // (128,6)
    const float* __restrict__ W_hh0,  // (128,32)
    const float* __restrict__ b_ih0,
    const float* __restrict__ b_hh0,
    const float* __restrict__ W_ih1,  // (128,32)
    const float* __restrict__ W_hh1,  // (128,32)
    const float* __restrict__ b_ih1,
    const float* __restrict__ b_hh1,
    const float* __restrict__ gamma,
    const float* __restrict__ beta,
    float* __restrict__ out)          // (B,32)
{
    const int tid = threadIdx.x;
    const int w   = tid >> 6;
    const int L   = w >> 1;        // 0: layer-0 role, 1: layer-1 role
    const int uh  = w & 1;         // unit half
    const int ln  = tid & 63;
    const int q   = ln >> 4;
    const int n   = ln & 15;
    const int u   = 16 * uh + n;
    const int b0  = blockIdx.x << 4;

    // fp16 h rings: [buf][m=16][k=unit padded to 40]
    __shared__ __align__(16) _Float16 h0r[2][16][40];
    __shared__ __align__(16) _Float16 h1r[2][16][40];
    // x staging: [buf][t in chunk][m=16][8 halves (6 data + 2 zero)]  = 32 KB
    __shared__ __align__(16) _Float16 xs[2][CH][16][8];
    __shared__ float ln_s[16][33];
    __shared__ __align__(8) float2 stab[1024];   // sigmoid table, 8 KB

    {   // zero h rings and xs pads
        unsigned* p0 = (unsigned*)&h0r[0][0][0];
        for (int i = tid; i < (int)(sizeof(h0r) / 4); i += 256) p0[i] = 0u;
        unsigned* p1 = (unsigned*)&h1r[0][0][0];
        for (int i = tid; i < (int)(sizeof(h1r) / 4); i += 256) p1[i] = 0u;
        unsigned* p2 = (unsigned*)&xs[0][0][0][0];
        for (int i = tid; i < (int)(sizeof(xs) / 4); i += 256) p2[i] = 0u;
        // sigmoid table (prologue-only cost; __expf fine here)
        for (int i = tid; i < 1024; i += 256) {
            float x0 = (float)(i - 512) * (1.0f / 32.0f);
            float v0 = 1.0f / (1.0f + __expf(-x0));
            float v1 = 1.0f / (1.0f + __expf(-(x0 + (1.0f / 32.0f))));
            stab[i] = make_float2(v0, v1 - v0);
        }
    }

    // table eval: u already = x*scale + 512
#define SIG_EVAL(res, uu) { \
        float u_ = __builtin_amdgcn_fmed3f((uu), 0.0f, 1022.99f); \
        int   i_ = (int)u_; \
        float f_ = u_ - (float)i_; \
        float2 e_ = stab[i_]; \
        res = fmaf(e_.y, f_, e_.x); }

    // ---------------- weight B-frags (fp16, 1-term) ----------------
    const float* Wa = L ? W_ih1 : W_hh0;
    const float* bi = L ? b_ih1 : b_ih0;
    const float* bh = L ? b_hh1 : b_hh0;

#define SETUP(p) \
    half8 Ba##p, Bb##p; float bias##p; { \
        const int g = 32 * (p) + u; \
        const float4* r4 = (const float4*)(Wa + g * 32 + 8 * q); \
        float4 va = r4[0], vb = r4[1]; \
        Ba##p = half8{(_Float16)va.x, (_Float16)va.y, (_Float16)va.z, (_Float16)va.w, \
                      (_Float16)vb.x, (_Float16)vb.y, (_Float16)vb.z, (_Float16)vb.w}; \
        Bb##p = half8{0, 0, 0, 0, 0, 0, 0, 0}; \
        if (L) { \
            const float4* s4 = (const float4*)(W_hh1 + g * 32 + 8 * q); \
            float4 sa = s4[0], sb = s4[1]; \
            Bb##p = half8{(_Float16)sa.x, (_Float16)sa.y, (_Float16)sa.z, (_Float16)sa.w, \
                          (_Float16)sb.x, (_Float16)sb.y, (_Float16)sb.z, (_Float16)sb.w}; \
        } else if (q == 0) { \
            const float* xw = W_ih0 + g * 6; \
            Bb##p[0] = (_Float16)xw[0]; Bb##p[1] = (_Float16)xw[1]; \
            Bb##p[2] = (_Float16)xw[2]; Bb##p[3] = (_Float16)xw[3]; \
            Bb##p[4] = (_Float16)xw[4]; Bb##p[5] = (_Float16)xw[5]; \
        } \
        bias##p = bi[g] + bh[g]; \
    }
    SETUP(0) SETUP(1) SETUP(2) SETUP(3)

    // ---------------- x chunk machinery (unchanged from R4) ----------------
    const int m0 = (tid       ) / 48, j0 = (tid       ) % 48;
    const int m1 = (tid + 256 ) / 48, j1 = (tid + 256 ) % 48;
    const int m2 = (tid + 512 ) / 48, j2 = (tid + 512 ) % 48;
    float4 xr0, xr1, xr2;

#define XLOAD(ch) { \
        const float* cb = x + (size_t)b0 * (TT * DD) + (ch) * (CH * DD); \
        xr0 = *(const float4*)(cb + (size_t)m0 * (TT * DD) + 4 * j0); \
        xr1 = *(const float4*)(cb + (size_t)m1 * (TT * DD) + 4 * j1); \
        xr2 = *(const float4*)(cb + (size_t)m2 * (TT * DD) + 4 * j2); }

#define XSTORE(buf) { \
        _Float16* xb_ = &xs[(buf)][0][0][0]; \
        { int f = 4 * j0; float4 v = xr0; \
          xb_[((f+0)/6)*128 + m0*8 + ((f+0)%6)] = (_Float16)v.x; \
          xb_[((f+1)/6)*128 + m0*8 + ((f+1)%6)] = (_Float16)v.y; \
          xb_[((f+2)/6)*128 + m0*8 + ((f+2)%6)] = (_Float16)v.z; \
          xb_[((f+3)/6)*128 + m0*8 + ((f+3)%6)] = (_Float16)v.w; } \
        { int f = 4 * j1; float4 v = xr1; \
          xb_[((f+0)/6)*128 + m1*8 + ((f+0)%6)] = (_Float16)v.x; \
          xb_[((f+1)/6)*128 + m1*8 + ((f+1)%6)] = (_Float16)v.y; \
          xb_[((f+2)/6)*128 + m1*8 + ((f+2)%6)] = (_Float16)v.z; \
          xb_[((f+3)/6)*128 + m1*8 + ((f+3)%6)] = (_Float16)v.w; } \
        { int f = 4 * j2; float4 v = xr2; \
          xb_[((f+0)/6)*128 + m2*8 + ((f+0)%6)] = (_Float16)v.x; \
          xb_[((f+1)/6)*128 + m2*8 + ((f+1)%6)] = (_Float16)v.y; \
          xb_[((f+2)/6)*128 + m2*8 + ((f+2)%6)] = (_Float16)v.z; \
          xb_[((f+3)/6)*128 + m2*8 + ((f+3)%6)] = (_Float16)v.w; } }

    XLOAD(0)
    XSTORE(0)

    float cc0 = 0.f, cc1 = 0.f, cc2 = 0.f, cc3 = 0.f;   // cell state (lane-local)
    float hL0 = 0.f, hL1 = 0.f, hL2 = 0.f, hL3 = 0.f;   // fp32 h1 (LN epilogue)

    __syncthreads();

    #pragma unroll 1
    for (int s = 0; s <= TT; ++s) {
        const int wsl = s & 1;
        const int rsl = wsl ^ 1;

        if ((s & (CH - 1)) == 0 && s < TT - CH) {
            XLOAD((s >> 5) + 1)
        }

        const bool active = L ? (s >= 1) : (s < TT);
        if (active) {
            half8 Aa = *(const half8*)&h0r[rsl][n][8 * q];
            half8 Ab;
            if (L) {
                Ab = *(const half8*)&h1r[wsl][n][8 * q];
            } else {
                Ab = half8{0, 0, 0, 0, 0, 0, 0, 0};
                if (q == 0)
                    Ab = *(const half8*)&xs[(s >> 5) & 1][s & (CH - 1)][n][0];
            }

#define GATE(p) \
            f32x4 acc##p = {bias##p, bias##p, bias##p, bias##p}; \
            acc##p = MFMA_F16(Aa, Ba##p, acc##p); \
            acc##p = MFMA_F16(Ab, Bb##p, acc##p);
            GATE(0) GATE(1) GATE(2) GATE(3)

            // table-based cell update; tanh(z) = 2*sig(2z)-1, 2x folded
            // into the index fma (scale 64 instead of 32).
#define UPD(r) { \
            float iv, fv, sg, ov, sc; \
            SIG_EVAL(iv, fmaf(acc0[r], 32.0f, 512.0f)); \
            SIG_EVAL(fv, fmaf(acc1[r], 32.0f, 512.0f)); \
            SIG_EVAL(sg, fmaf(acc2[r], 64.0f, 512.0f)); \
            SIG_EVAL(ov, fmaf(acc3[r], 32.0f, 512.0f)); \
            float tg = fmaf(2.0f, sg, -1.0f); \
            cc##r = fmaf(fv, cc##r, iv * tg); \
            SIG_EVAL(sc, fmaf(cc##r, 64.0f, 512.0f)); \
            float h_ = ov * fmaf(2.0f, sc, -1.0f); \
            if (L) { hL##r = h_; h1r[rsl][4 * q + r][u] = (_Float16)h_; } \
            else   {             h0r[wsl][4 * q + r][u] = (_Float16)h_; } }
            UPD(0) UPD(1) UPD(2) UPD(3)
        }

        if ((s & (CH - 1)) == CH - 1 && s < TT - 1) {
            XSTORE(((s >> 5) + 1) & 1)
        }

        __syncthreads();
    }

    // ---------------- LayerNorm epilogue ----------------
    if (L) {
        ln_s[4 * q + 0][u] = hL0;
        ln_s[4 * q + 1][u] = hL1;
        ln_s[4 * q + 2][u] = hL2;
        ln_s[4 * q + 3][u] = hL3;
    }
    __syncthreads();

    if (tid < 16) {
        const int m = tid;
        float s = 0.f, s2 = 0.f;
        #pragma unroll
        for (int k = 0; k < HD; ++k) {
            float v = ln_s[m][k];
            s += v; s2 += v * v;
        }
        float mu  = s * (1.0f / HD);
        float var = s2 * (1.0f / HD) - mu * mu;
        float rr  = rsqrtf(var + EPSL);
        float* op = out + (size_t)(b0 + m) * HD;
        #pragma unroll
        for (int k = 0; k < HD; ++k)
            op[k] = (ln_s[m][k] - mu) * rr * gamma[k] + beta[k];
    }
}

extern "C" void kernel_launch(void* const* d_in, const int* in_sizes, int n_in,
                              void* d_out, int out_size, void* d_ws, size_t ws_size,
                              hipStream_t stream) {
    const float* x     = (const float*)d_in[0];
    const float* W_ih0 = (const float*)d_in[1];
    const float* W_hh0 = (const float*)d_in[2];
    const float* b_ih0 = (const float*)d_in[3];
    const float* b_hh0 = (const float*)d_in[4];
    const float* W_ih1 = (const float*)d_in[5];
    const float* W_hh1 = (const float*)d_in[6];
    const float* b_ih1 = (const float*)d_in[7];
    const float* b_hh1 = (const float*)d_in[8];
    const float* gamma = (const float*)d_in[9];
    const float* beta  = (const float*)d_in[10];
    float* out = (float*)d_out;

    const int B = in_sizes[0] / (TT * DD);   // 4096
    lstm2_pipe<<<B / 16, 256, 0, stream>>>(x, W_ih0, W_hh0, b_ih0, b_hh0,
                                           W_ih1, W_hh1, b_ih1, b_hh1,
                                           gamma, beta, out);
}

// Round 6
// 330.514 us; speedup vs baseline: 1.6948x; 1.6948x over previous
//
#include <hip/hip_runtime.h>

#define TT   512
#define DD   6
#define HD   32
#define CH   32          // x-staging chunk (timesteps)
#define EPSL 1e-5f

typedef _Float16 half8 __attribute__((ext_vector_type(8)));
typedef __attribute__((ext_vector_type(4))) float f32x4;

#define MFMA_F16(a, b, c) __builtin_amdgcn_mfma_f32_16x16x32_f16((a), (b), (c), 0, 0, 0)

// ====================================================================
// R6 = R4 (exp-based activations; R5's LDS table regressed: divergent
// gathers serialize the shared per-CU LDS pipe + 120cy latency in the
// recurrence chain) + two issue cuts:
//  (1) activation scales folded into pre-scaled weights; bias folded into
//      a per-lane constant K = 2^(scale*bias):  sig(z) = rcp(fma(K, 2^acc, 1))
//      -> no per-eval mul, no bias splat, no add.
//  (2) s-loop unrolled x2 so ring-slot indices are compile-time -> LDS
//      addresses hoisted; XLOAD only in even body, XSTORE only in odd.
// ====================================================================
__global__ __launch_bounds__(256, 1) void lstm2_pipe(
    const float* __restrict__ x,      // (B,512,6)
    const float* __restrict__ W_ih0,  // (128,6)
    const float* __restrict__ W_hh0,  // (128,32)
    const float* __restrict__ b_ih0,
    const float* __restrict__ b_hh0,
    const float* __restrict__ W_ih1,  // (128,32)
    const float* __restrict__ W_hh1,  // (128,32)
    const float* __restrict__ b_ih1,
    const float* __restrict__ b_hh1,
    const float* __restrict__ gamma,
    const float* __restrict__ beta,
    float* __restrict__ out)          // (B,32)
{
    const int tid = threadIdx.x;
    const int w   = tid >> 6;
    const int L   = w >> 1;        // 0: layer-0 role, 1: layer-1 role
    const int uh  = w & 1;         // unit half
    const int ln  = tid & 63;
    const int q   = ln >> 4;
    const int n   = ln & 15;
    const int u   = 16 * uh + n;
    const int b0  = blockIdx.x << 4;

    // fp16 h rings: [buf][m=16][k=unit padded to 40]
    __shared__ __align__(16) _Float16 h0r[2][16][40];
    __shared__ __align__(16) _Float16 h1r[2][16][40];
    // x staging: [buf][t in chunk][m=16][8 halves (6 data + 2 zero)]
    __shared__ __align__(16) _Float16 xs[2][CH][16][8];
    __shared__ float ln_s[16][33];

    {   // zero h rings and xs pads
        unsigned* p0 = (unsigned*)&h0r[0][0][0];
        for (int i = tid; i < (int)(sizeof(h0r) / 4); i += 256) p0[i] = 0u;
        unsigned* p1 = (unsigned*)&h1r[0][0][0];
        for (int i = tid; i < (int)(sizeof(h1r) / 4); i += 256) p1[i] = 0u;
        unsigned* p2 = (unsigned*)&xs[0][0][0][0];
        for (int i = tid; i < (int)(sizeof(xs) / 4); i += 256) p2[i] = 0u;
    }

    // ---------------- weight B-frags (fp16, pre-scaled) ----------------
    // p in {0,1,3} (i,f,o): scale -log2(e);  p=2 (g, tanh): -2*log2(e).
    const float* Wa = L ? W_ih1 : W_hh0;
    const float* bi = L ? b_ih1 : b_ih0;
    const float* bh = L ? b_hh1 : b_hh0;

#define SETUP(p, SC) \
    half8 Ba##p, Bb##p; float K##p; { \
        const int g = 32 * (p) + u; \
        const float4* r4 = (const float4*)(Wa + g * 32 + 8 * q); \
        float4 va = r4[0], vb = r4[1]; \
        Ba##p = half8{(_Float16)(SC * va.x), (_Float16)(SC * va.y), \
                      (_Float16)(SC * va.z), (_Float16)(SC * va.w), \
                      (_Float16)(SC * vb.x), (_Float16)(SC * vb.y), \
                      (_Float16)(SC * vb.z), (_Float16)(SC * vb.w)}; \
        Bb##p = half8{0, 0, 0, 0, 0, 0, 0, 0}; \
        if (L) { \
            const float4* s4 = (const float4*)(W_hh1 + g * 32 + 8 * q); \
            float4 sa = s4[0], sb = s4[1]; \
            Bb##p = half8{(_Float16)(SC * sa.x), (_Float16)(SC * sa.y), \
                          (_Float16)(SC * sa.z), (_Float16)(SC * sa.w), \
                          (_Float16)(SC * sb.x), (_Float16)(SC * sb.y), \
                          (_Float16)(SC * sb.z), (_Float16)(SC * sb.w)}; \
        } else if (q == 0) { \
            const float* xw = W_ih0 + g * 6; \
            Bb##p[0] = (_Float16)(SC * xw[0]); Bb##p[1] = (_Float16)(SC * xw[1]); \
            Bb##p[2] = (_Float16)(SC * xw[2]); Bb##p[3] = (_Float16)(SC * xw[3]); \
            Bb##p[4] = (_Float16)(SC * xw[4]); Bb##p[5] = (_Float16)(SC * xw[5]); \
        } \
        K##p = __builtin_amdgcn_exp2f(SC * (bi[g] + bh[g])); \
    }
    SETUP(0, -1.44269504f) SETUP(1, -1.44269504f)
    SETUP(2, -2.88539008f) SETUP(3, -1.44269504f)

    // ---------------- x chunk machinery (R4) ----------------
    const int m0 = (tid       ) / 48, j0 = (tid       ) % 48;
    const int m1 = (tid + 256 ) / 48, j1 = (tid + 256 ) % 48;
    const int m2 = (tid + 512 ) / 48, j2 = (tid + 512 ) % 48;
    float4 xr0, xr1, xr2;

#define XLOAD(ch) { \
        const float* cb = x + (size_t)b0 * (TT * DD) + (ch) * (CH * DD); \
        xr0 = *(const float4*)(cb + (size_t)m0 * (TT * DD) + 4 * j0); \
        xr1 = *(const float4*)(cb + (size_t)m1 * (TT * DD) + 4 * j1); \
        xr2 = *(const float4*)(cb + (size_t)m2 * (TT * DD) + 4 * j2); }

#define XSTORE(buf) { \
        _Float16* xb_ = &xs[(buf)][0][0][0]; \
        { int f = 4 * j0; float4 v = xr0; \
          xb_[((f+0)/6)*128 + m0*8 + ((f+0)%6)] = (_Float16)v.x; \
          xb_[((f+1)/6)*128 + m0*8 + ((f+1)%6)] = (_Float16)v.y; \
          xb_[((f+2)/6)*128 + m0*8 + ((f+2)%6)] = (_Float16)v.z; \
          xb_[((f+3)/6)*128 + m0*8 + ((f+3)%6)] = (_Float16)v.w; } \
        { int f = 4 * j1; float4 v = xr1; \
          xb_[((f+0)/6)*128 + m1*8 + ((f+0)%6)] = (_Float16)v.x; \
          xb_[((f+1)/6)*128 + m1*8 + ((f+1)%6)] = (_Float16)v.y; \
          xb_[((f+2)/6)*128 + m1*8 + ((f+2)%6)] = (_Float16)v.z; \
          xb_[((f+3)/6)*128 + m1*8 + ((f+3)%6)] = (_Float16)v.w; } \
        { int f = 4 * j2; float4 v = xr2; \
          xb_[((f+0)/6)*128 + m2*8 + ((f+0)%6)] = (_Float16)v.x; \
          xb_[((f+1)/6)*128 + m2*8 + ((f+1)%6)] = (_Float16)v.y; \
          xb_[((f+2)/6)*128 + m2*8 + ((f+2)%6)] = (_Float16)v.z; \
          xb_[((f+3)/6)*128 + m2*8 + ((f+3)%6)] = (_Float16)v.w; } }

    XLOAD(0)
    XSTORE(0)

    float cc0 = 0.f, cc1 = 0.f, cc2 = 0.f, cc3 = 0.f;   // cell state (lane-local)
    float hL0 = 0.f, hL1 = 0.f, hL2 = 0.f, hL3 = 0.f;   // fp32 h1 (LN epilogue)

    __syncthreads();

#define GATE(p) \
    f32x4 acc##p = {0.f, 0.f, 0.f, 0.f}; \
    acc##p = MFMA_F16(Aa, Ba##p, acc##p); \
    acc##p = MFMA_F16(Ab, Bb##p, acc##p);

    // sig(z+b) = rcp(1 + 2^(-1.4427(z+b))) = rcp(fma(K, 2^acc, 1)),
    // acc = -1.4427*z from pre-scaled weights. tanh analog at 2x scale.
#define UPD(r, IS_L1, WS) { \
        float e0 = __builtin_amdgcn_exp2f(acc0[r]); \
        float e1 = __builtin_amdgcn_exp2f(acc1[r]); \
        float e2 = __builtin_amdgcn_exp2f(acc2[r]); \
        float e3 = __builtin_amdgcn_exp2f(acc3[r]); \
        float iv = __builtin_amdgcn_rcpf(fmaf(K0, e0, 1.0f)); \
        float fv = __builtin_amdgcn_rcpf(fmaf(K1, e1, 1.0f)); \
        float tg = fmaf(2.0f, __builtin_amdgcn_rcpf(fmaf(K2, e2, 1.0f)), -1.0f); \
        float ov = __builtin_amdgcn_rcpf(fmaf(K3, e3, 1.0f)); \
        cc##r = fmaf(fv, cc##r, iv * tg); \
        float ec = __builtin_amdgcn_exp2f(cc##r * -2.88539008f); \
        float tc = fmaf(2.0f, __builtin_amdgcn_rcpf(1.0f + ec), -1.0f); \
        float h_ = ov * tc; \
        if (IS_L1) { hL##r = h_; h1r[WS][4 * q + r][u] = (_Float16)h_; } \
        else       {             h0r[WS][4 * q + r][u] = (_Float16)h_; } }

    // RSL/WSL are compile-time constants per unrolled body.
#define STEP(RSL, WSL, S) \
    if (L) { \
        if ((S) >= 1 && (S) <= TT) { \
            half8 Aa = *(const half8*)&h0r[RSL][n][8 * q]; \
            half8 Ab = *(const half8*)&h1r[WSL][n][8 * q]; \
            GATE(0) GATE(1) GATE(2) GATE(3) \
            UPD(0, 1, RSL) UPD(1, 1, RSL) UPD(2, 1, RSL) UPD(3, 1, RSL) \
        } \
    } else { \
        if ((S) < TT) { \
            half8 Aa = *(const half8*)&h0r[RSL][n][8 * q]; \
            half8 Ab = half8{0, 0, 0, 0, 0, 0, 0, 0}; \
            if (q == 0) Ab = *(const half8*)&xs[((S) >> 5) & 1][(S) & (CH - 1)][n][0]; \
            GATE(0) GATE(1) GATE(2) GATE(3) \
            UPD(0, 0, WSL) UPD(1, 0, WSL) UPD(2, 0, WSL) UPD(3, 0, WSL) \
        } \
    }

    #pragma unroll 1
    for (int s = 0; s < 514; s += 2) {
        // even body: wsl=0, rsl=1
        if ((s & (CH - 1)) == 0 && s < TT - CH) { XLOAD((s >> 5) + 1) }
        STEP(1, 0, s)
        __syncthreads();

        // odd body: wsl=1, rsl=0
        const int so = s + 1;
        STEP(0, 1, so)
        if ((so & (CH - 1)) == CH - 1 && so < TT - 1) { XSTORE(((so >> 5) + 1) & 1) }
        __syncthreads();
    }

    // ---------------- LayerNorm epilogue ----------------
    if (L) {
        ln_s[4 * q + 0][u] = hL0;
        ln_s[4 * q + 1][u] = hL1;
        ln_s[4 * q + 2][u] = hL2;
        ln_s[4 * q + 3][u] = hL3;
    }
    __syncthreads();

    if (tid < 16) {
        const int m = tid;
        float s = 0.f, s2 = 0.f;
        #pragma unroll
        for (int k = 0; k < HD; ++k) {
            float v = ln_s[m][k];
            s += v; s2 += v * v;
        }
        float mu  = s * (1.0f / HD);
        float var = s2 * (1.0f / HD) - mu * mu;
        float rr  = rsqrtf(var + EPSL);
        float* op = out + (size_t)(b0 + m) * HD;
        #pragma unroll
        for (int k = 0; k < HD; ++k)
            op[k] = (ln_s[m][k] - mu) * rr * gamma[k] + beta[k];
    }
}

extern "C" void kernel_launch(void* const* d_in, const int* in_sizes, int n_in,
                              void* d_out, int out_size, void* d_ws, size_t ws_size,
                              hipStream_t stream) {
    const float* x     = (const float*)d_in[0];
    const float* W_ih0 = (const float*)d_in[1];
    const float* W_hh0 = (const float*)d_in[2];
    const float* b_ih0 = (const float*)d_in[3];
    const float* b_hh0 = (const float*)d_in[4];
    const float* W_ih1 = (const float*)d_in[5];
    const float* W_hh1 = (const float*)d_in[6];
    const float* b_ih1 = (const float*)d_in[7];
    const float* b_hh1 = (const float*)d_in[8];
    const float* gamma = (const float*)d_in[9];
    const float* beta  = (const float*)d_in[10];
    float* out = (float*)d_out;

    const int B = in_sizes[0] / (TT * DD);   // 4096
    lstm2_pipe<<<B / 16, 256, 0, stream>>>(x, W_ih0, W_hh0, b_ih0, b_hh0,
                                           W_ih1, W_hh1, b_ih1, b_hh1,
                                           gamma, beta, out);
}

// Round 7
// 312.313 us; speedup vs baseline: 1.7935x; 1.0583x over previous
//
#include <hip/hip_runtime.h>

#define TT   512
#define DD   6
#define HD   32
#define CH   32          // x-staging chunk (timesteps)
#define EPSL 1e-5f
#define L2E  1.44269504f
#define L2E2 2.88539008f

typedef _Float16 half8 __attribute__((ext_vector_type(8)));
typedef __attribute__((ext_vector_type(4))) float f32x4;

#define MFMA_F16(a, b, c) __builtin_amdgcn_mfma_f32_16x16x32_f16((a), (b), (c), 0, 0, 0)

// ====================================================================
// R7 = R6 + (1) rcp-merged cell update: 7 trans/cell instead of 10
//   c' = [c(1+A)(1+B) + (1-B)(1+F)] / [(1+F)(1+A)(1+B)]   (1 rcp)
//   h  = (1-C) / [(1+O)(1+C)]                              (1 rcp)
//   with c kept PRE-SCALED by -2*log2(e) so ec = exp2(c_s) directly;
//   the -2.885 on the numerator's Q-term folds into constant K2c.
// (2) L1 skew-2 (t1 = s-2) + 4-slot h0 ring -> L1's h0 A-frag read is
//   issued at the END of the previous iteration (data >=1 barrier old,
//   race-free); its ~120cy LDS latency is absorbed into the barrier wait.
// (3) loop unrolled x4 so all ring slots are compile-time.
// ====================================================================
__global__ __launch_bounds__(256, 1) void lstm2_pipe(
    const float* __restrict__ x,      // (B,512,6)
    const float* __restrict__ W_ih0,  // (128,6)
    const float* __restrict__ W_hh0,  // (128,32)
    const float* __restrict__ b_ih0,
    const float* __restrict__ b_hh0,
    const float* __restrict__ W_ih1,  // (128,32)
    const float* __restrict__ W_hh1,  // (128,32)
    const float* __restrict__ b_ih1,
    const float* __restrict__ b_hh1,
    const float* __restrict__ gamma,
    const float* __restrict__ beta,
    float* __restrict__ out)          // (B,32)
{
    const int tid = threadIdx.x;
    const int w   = tid >> 6;
    const int L   = w >> 1;        // 0: layer-0 role, 1: layer-1 role
    const int uh  = w & 1;         // unit half
    const int ln  = tid & 63;
    const int q   = ln >> 4;
    const int n   = ln & 15;
    const int u   = 16 * uh + n;
    const int b0  = blockIdx.x << 4;

    // h0 ring: 4 slots (skew-2 pipeline). h1 ring: 2 slots.
    __shared__ __align__(16) _Float16 h0r[4][16][40];
    __shared__ __align__(16) _Float16 h1r[2][16][40];
    __shared__ __align__(16) _Float16 xs[2][CH][16][8];
    __shared__ float ln_s[16][33];

    {   // zero rings and xs pads
        unsigned* p0 = (unsigned*)&h0r[0][0][0];
        for (int i = tid; i < (int)(sizeof(h0r) / 4); i += 256) p0[i] = 0u;
        unsigned* p1 = (unsigned*)&h1r[0][0][0];
        for (int i = tid; i < (int)(sizeof(h1r) / 4); i += 256) p1[i] = 0u;
        unsigned* p2 = (unsigned*)&xs[0][0][0][0];
        for (int i = tid; i < (int)(sizeof(xs) / 4); i += 256) p2[i] = 0u;
    }

    // ---------------- weight B-frags (fp16, pre-scaled) ----------------
    const float* Wa = L ? W_ih1 : W_hh0;
    const float* bi = L ? b_ih1 : b_ih0;
    const float* bh = L ? b_hh1 : b_hh0;

#define SETUP(p, SC) \
    half8 Ba##p, Bb##p; float K##p; { \
        const int g = 32 * (p) + u; \
        const float4* r4 = (const float4*)(Wa + g * 32 + 8 * q); \
        float4 va = r4[0], vb = r4[1]; \
        Ba##p = half8{(_Float16)(SC * va.x), (_Float16)(SC * va.y), \
                      (_Float16)(SC * va.z), (_Float16)(SC * va.w), \
                      (_Float16)(SC * vb.x), (_Float16)(SC * vb.y), \
                      (_Float16)(SC * vb.z), (_Float16)(SC * vb.w)}; \
        Bb##p = half8{0, 0, 0, 0, 0, 0, 0, 0}; \
        if (L) { \
            const float4* s4 = (const float4*)(W_hh1 + g * 32 + 8 * q); \
            float4 sa = s4[0], sb = s4[1]; \
            Bb##p = half8{(_Float16)(SC * sa.x), (_Float16)(SC * sa.y), \
                          (_Float16)(SC * sa.z), (_Float16)(SC * sa.w), \
                          (_Float16)(SC * sb.x), (_Float16)(SC * sb.y), \
                          (_Float16)(SC * sb.z), (_Float16)(SC * sb.w)}; \
        } else if (q == 0) { \
            const float* xw = W_ih0 + g * 6; \
            Bb##p[0] = (_Float16)(SC * xw[0]); Bb##p[1] = (_Float16)(SC * xw[1]); \
            Bb##p[2] = (_Float16)(SC * xw[2]); Bb##p[3] = (_Float16)(SC * xw[3]); \
            Bb##p[4] = (_Float16)(SC * xw[4]); Bb##p[5] = (_Float16)(SC * xw[5]); \
        } \
        K##p = __builtin_amdgcn_exp2f(SC * (bi[g] + bh[g])); \
    }
    SETUP(0, -L2E) SETUP(1, -L2E) SETUP(2, -L2E2) SETUP(3, -L2E)
    const float K2c = L2E2 * K2;   // for the scaled (1-B) term

    // ---------------- x chunk machinery ----------------
    const int m0 = (tid       ) / 48, j0 = (tid       ) % 48;
    const int m1 = (tid + 256 ) / 48, j1 = (tid + 256 ) % 48;
    const int m2 = (tid + 512 ) / 48, j2 = (tid + 512 ) % 48;
    float4 xr0, xr1, xr2;

#define XLOAD(ch) { \
        const float* cb = x + (size_t)b0 * (TT * DD) + (ch) * (CH * DD); \
        xr0 = *(const float4*)(cb + (size_t)m0 * (TT * DD) + 4 * j0); \
        xr1 = *(const float4*)(cb + (size_t)m1 * (TT * DD) + 4 * j1); \
        xr2 = *(const float4*)(cb + (size_t)m2 * (TT * DD) + 4 * j2); }

#define XSTORE(buf) { \
        _Float16* xb_ = &xs[(buf)][0][0][0]; \
        { int f = 4 * j0; float4 v = xr0; \
          xb_[((f+0)/6)*128 + m0*8 + ((f+0)%6)] = (_Float16)v.x; \
          xb_[((f+1)/6)*128 + m0*8 + ((f+1)%6)] = (_Float16)v.y; \
          xb_[((f+2)/6)*128 + m0*8 + ((f+2)%6)] = (_Float16)v.z; \
          xb_[((f+3)/6)*128 + m0*8 + ((f+3)%6)] = (_Float16)v.w; } \
        { int f = 4 * j1; float4 v = xr1; \
          xb_[((f+0)/6)*128 + m1*8 + ((f+0)%6)] = (_Float16)v.x; \
          xb_[((f+1)/6)*128 + m1*8 + ((f+1)%6)] = (_Float16)v.y; \
          xb_[((f+2)/6)*128 + m1*8 + ((f+2)%6)] = (_Float16)v.z; \
          xb_[((f+3)/6)*128 + m1*8 + ((f+3)%6)] = (_Float16)v.w; } \
        { int f = 4 * j2; float4 v = xr2; \
          xb_[((f+0)/6)*128 + m2*8 + ((f+0)%6)] = (_Float16)v.x; \
          xb_[((f+1)/6)*128 + m2*8 + ((f+1)%6)] = (_Float16)v.y; \
          xb_[((f+2)/6)*128 + m2*8 + ((f+2)%6)] = (_Float16)v.z; \
          xb_[((f+3)/6)*128 + m2*8 + ((f+3)%6)] = (_Float16)v.w; } }

    XLOAD(0)
    XSTORE(0)

    float cc0 = 0.f, cc1 = 0.f, cc2 = 0.f, cc3 = 0.f;   // c, PRE-SCALED by -2*log2e
    float hL0 = 0.f, hL1 = 0.f, hL2 = 0.f, hL3 = 0.f;   // fp32 h1 (LN epilogue)
    half8 AaN = {0,0,0,0,0,0,0,0};                       // L1's prefetched h0 frag

    __syncthreads();

#define GATE(p) \
    f32x4 acc##p = {0.f, 0.f, 0.f, 0.f}; \
    acc##p = MFMA_F16(Aa, Ba##p, acc##p); \
    acc##p = MFMA_F16(Ab, Bb##p, acc##p);

    // rcp-merged update. A=K0*e0, F=K1*e1, B=K2*e2, O=K3*e3.
#define UPD(r, IS_L1, WS) { \
        float e0 = __builtin_amdgcn_exp2f(acc0[r]); \
        float e1 = __builtin_amdgcn_exp2f(acc1[r]); \
        float e2 = __builtin_amdgcn_exp2f(acc2[r]); \
        float e3 = __builtin_amdgcn_exp2f(acc3[r]); \
        float pA = fmaf(K0, e0, 1.0f); \
        float pF = fmaf(K1, e1, 1.0f); \
        float pB = fmaf(K2, e2, 1.0f); \
        float pO = fmaf(K3, e3, 1.0f); \
        float Qh = fmaf(K2c, e2, -L2E2);      /* = -2.885*(1-B) */ \
        float P  = pA * pB; \
        float R  = __builtin_amdgcn_rcpf(P * pF); \
        float nm = fmaf(cc##r, P, Qh * pF); \
        cc##r = nm * R;                        /* scaled c' */ \
        float ec = __builtin_amdgcn_exp2f(cc##r); \
        float R2 = __builtin_amdgcn_rcpf(pO * (1.0f + ec)); \
        float h_ = (1.0f - ec) * R2; \
        if (IS_L1) { hL##r = h_; h1r[WS][4 * q + r][u] = (_Float16)h_; } \
        else       {             h0r[WS][4 * q + r][u] = (_Float16)h_; } }

    // Body J (s = s0+J): compile-time slots.
    //  L0 (s<TT):  Aa = h0[(J+3)&3] (h0(s-1)), write h0[J&3].
    //  L1 (2<=s<TT+2): t1=s-2. Aa = AaN (prefetched h0(s-2)),
    //    Ab = h1[(J+1)&1] (h1(s-3)), write h1[J&1]; then prefetch
    //    AaN = h0[(J+3)&3] = h0(s-1) for next iter (pre-barrier, safe).
#define BODY(J, S) { \
        if ((J) == 0 && ((S) & (CH - 1)) == 0 && (S) < TT - CH) { XLOAD(((S) >> 5) + 1) } \
        if (L) { \
            if ((S) >= 2 && (S) < TT + 2) { \
                half8 Aa = AaN; \
                half8 Ab = *(const half8*)&h1r[((J) + 1) & 1][n][8 * q]; \
                GATE(0) GATE(1) GATE(2) GATE(3) \
                UPD(0, 1, (J) & 1) UPD(1, 1, (J) & 1) \
                UPD(2, 1, (J) & 1) UPD(3, 1, (J) & 1) \
            } \
            AaN = *(const half8*)&h0r[((J) + 3) & 3][n][8 * q]; \
        } else { \
            if ((S) < TT) { \
                half8 Aa = *(const half8*)&h0r[((J) + 3) & 3][n][8 * q]; \
                half8 Ab = half8{0, 0, 0, 0, 0, 0, 0, 0}; \
                if (q == 0) Ab = *(const half8*)&xs[((S) >> 5) & 1][(S) & (CH - 1)][n][0]; \
                GATE(0) GATE(1) GATE(2) GATE(3) \
                UPD(0, 0, (J) & 3) UPD(1, 0, (J) & 3) \
                UPD(2, 0, (J) & 3) UPD(3, 0, (J) & 3) \
            } \
        } \
        if ((J) == 3 && (((S) & (CH - 1)) == CH - 1) && (S) < TT - 1) { XSTORE((((S) >> 5) + 1) & 1) } \
        __syncthreads(); }

    #pragma unroll 1
    for (int s0 = 0; s0 < 516; s0 += 4) {
        BODY(0, s0)
        BODY(1, s0 + 1)
        BODY(2, s0 + 2)
        BODY(3, s0 + 3)
    }

    // ---------------- LayerNorm epilogue ----------------
    if (L) {
        ln_s[4 * q + 0][u] = hL0;
        ln_s[4 * q + 1][u] = hL1;
        ln_s[4 * q + 2][u] = hL2;
        ln_s[4 * q + 3][u] = hL3;
    }
    __syncthreads();

    if (tid < 16) {
        const int m = tid;
        float s = 0.f, s2 = 0.f;
        #pragma unroll
        for (int k = 0; k < HD; ++k) {
            float v = ln_s[m][k];
            s += v; s2 += v * v;
        }
        float mu  = s * (1.0f / HD);
        float var = s2 * (1.0f / HD) - mu * mu;
        float rr  = rsqrtf(var + EPSL);
        float* op = out + (size_t)(b0 + m) * HD;
        #pragma unroll
        for (int k = 0; k < HD; ++k)
            op[k] = (ln_s[m][k] - mu) * rr * gamma[k] + beta[k];
    }
}

extern "C" void kernel_launch(void* const* d_in, const int* in_sizes, int n_in,
                              void* d_out, int out_size, void* d_ws, size_t ws_size,
                              hipStream_t stream) {
    const float* x     = (const float*)d_in[0];
    const float* W_ih0 = (const float*)d_in[1];
    const float* W_hh0 = (const float*)d_in[2];
    const float* b_ih0 = (const float*)d_in[3];
    const float* b_hh0 = (const float*)d_in[4];
    const float* W_ih1 = (const float*)d_in[5];
    const float* W_hh1 = (const float*)d_in[6];
    const float* b_ih1 = (const float*)d_in[7];
    const float* b_hh1 = (const float*)d_in[8];
    const float* gamma = (const float*)d_in[9];
    const float* beta  = (const float*)d_in[10];
    float* out = (float*)d_out;

    const int B = in_sizes[0] / (TT * DD);   // 4096
    lstm2_pipe<<<B / 16, 256, 0, stream>>>(x, W_ih0, W_hh0, b_ih0, b_hh0,
                                           W_ih1, W_hh1, b_ih1, b_hh1,
                                           gamma, beta, out);
}

// Round 9
// 306.943 us; speedup vs baseline: 1.8249x; 1.0175x over previous
//
#include <hip/hip_runtime.h>

#define TT   512
#define DD   6
#define HD   32
#define CH   32          // x-staging chunk (timesteps)
#define EPSL 1e-5f
#define L2E  1.44269504f
#define L2E2 2.88539008f

typedef _Float16 half8 __attribute__((ext_vector_type(8)));
typedef __attribute__((ext_vector_type(4))) float f32x4;

#define MFMA_F16(a, b, c) __builtin_amdgcn_mfma_f32_16x16x32_f16((a), (b), (c), 0, 0, 0)

// ====================================================================
// R9 = R8 with the bug fixed: XSTORE is a COOPERATIVE 256-thread scatter
// (threads tid, tid+256, tid+512 cover a chunk's 768 float4). R8 put it
// inside the L0-only else-branch -> only 128 threads stored, half of xs
// stale -> absmax 0.868. It must sit OUTSIDE the role branch (as in R7).
// R8's actual optimizations, retained:
//  (1) L0 x-frag prefetched into regs (AbN) at END of prior body —
//      legal because XSTORE runs at s%32==30, so the xs slot for s+1
//      is always >=1 barrier old. L0 post-barrier LDS reads: 2 -> 1.
//  (2) reg-frag MFMA issued FIRST per gate -> the irreducible
//      self-recurrence ds_read (~120cy) hides under 4 MFMAs.
//  (3) persistent ZACC zero-register kills 16 v_mov acc-inits/iter.
// ====================================================================
__global__ __launch_bounds__(256, 1) void lstm2_pipe(
    const float* __restrict__ x,      // (B,512,6)
    const float* __restrict__ W_ih0,  // (128,6)
    const float* __restrict__ W_hh0,  // (128,32)
    const float* __restrict__ b_ih0,
    const float* __restrict__ b_hh0,
    const float* __restrict__ W_ih1,  // (128,32)
    const float* __restrict__ W_hh1,  // (128,32)
    const float* __restrict__ b_ih1,
    const float* __restrict__ b_hh1,
    const float* __restrict__ gamma,
    const float* __restrict__ beta,
    float* __restrict__ out)          // (B,32)
{
    const int tid = threadIdx.x;
    const int w   = tid >> 6;
    const int L   = w >> 1;        // 0: layer-0 role, 1: layer-1 role
    const int uh  = w & 1;         // unit half
    const int ln  = tid & 63;
    const int q   = ln >> 4;
    const int n   = ln & 15;
    const int u   = 16 * uh + n;
    const int b0  = blockIdx.x << 4;

    __shared__ __align__(16) _Float16 h0r[4][16][40];
    __shared__ __align__(16) _Float16 h1r[2][16][40];
    __shared__ __align__(16) _Float16 xs[2][CH][16][8];
    __shared__ float ln_s[16][33];

    {   // zero rings and xs pads
        unsigned* p0 = (unsigned*)&h0r[0][0][0];
        for (int i = tid; i < (int)(sizeof(h0r) / 4); i += 256) p0[i] = 0u;
        unsigned* p1 = (unsigned*)&h1r[0][0][0];
        for (int i = tid; i < (int)(sizeof(h1r) / 4); i += 256) p1[i] = 0u;
        unsigned* p2 = (unsigned*)&xs[0][0][0][0];
        for (int i = tid; i < (int)(sizeof(xs) / 4); i += 256) p2[i] = 0u;
    }
    __syncthreads();   // xs fully zeroed before the prologue XSTORE(0)

    // ---------------- weight B-frags (fp16, pre-scaled) ----------------
    const float* Wa = L ? W_ih1 : W_hh0;
    const float* bi = L ? b_ih1 : b_ih0;
    const float* bh = L ? b_hh1 : b_hh0;

#define SETUP(p, SC) \
    half8 Ba##p, Bb##p; float K##p; { \
        const int g = 32 * (p) + u; \
        const float4* r4 = (const float4*)(Wa + g * 32 + 8 * q); \
        float4 va = r4[0], vb = r4[1]; \
        Ba##p = half8{(_Float16)(SC * va.x), (_Float16)(SC * va.y), \
                      (_Float16)(SC * va.z), (_Float16)(SC * va.w), \
                      (_Float16)(SC * vb.x), (_Float16)(SC * vb.y), \
                      (_Float16)(SC * vb.z), (_Float16)(SC * vb.w)}; \
        Bb##p = half8{0, 0, 0, 0, 0, 0, 0, 0}; \
        if (L) { \
            const float4* s4 = (const float4*)(W_hh1 + g * 32 + 8 * q); \
            float4 sa = s4[0], sb = s4[1]; \
            Bb##p = half8{(_Float16)(SC * sa.x), (_Float16)(SC * sa.y), \
                          (_Float16)(SC * sa.z), (_Float16)(SC * sa.w), \
                          (_Float16)(SC * sb.x), (_Float16)(SC * sb.y), \
                          (_Float16)(SC * sb.z), (_Float16)(SC * sb.w)}; \
        } else if (q == 0) { \
            const float* xw = W_ih0 + g * 6; \
            Bb##p[0] = (_Float16)(SC * xw[0]); Bb##p[1] = (_Float16)(SC * xw[1]); \
            Bb##p[2] = (_Float16)(SC * xw[2]); Bb##p[3] = (_Float16)(SC * xw[3]); \
            Bb##p[4] = (_Float16)(SC * xw[4]); Bb##p[5] = (_Float16)(SC * xw[5]); \
        } \
        K##p = __builtin_amdgcn_exp2f(SC * (bi[g] + bh[g])); \
    }
    SETUP(0, -L2E) SETUP(1, -L2E) SETUP(2, -L2E2) SETUP(3, -L2E)
    const float K2c = L2E2 * K2;

    // ---------------- x chunk machinery (cooperative, all 256 threads) ----
    const int m0 = (tid       ) / 48, j0 = (tid       ) % 48;
    const int m1 = (tid + 256 ) / 48, j1 = (tid + 256 ) % 48;
    const int m2 = (tid + 512 ) / 48, j2 = (tid + 512 ) % 48;
    float4 xr0, xr1, xr2;

#define XLOAD(ch) { \
        const float* cb = x + (size_t)b0 * (TT * DD) + (ch) * (CH * DD); \
        xr0 = *(const float4*)(cb + (size_t)m0 * (TT * DD) + 4 * j0); \
        xr1 = *(const float4*)(cb + (size_t)m1 * (TT * DD) + 4 * j1); \
        xr2 = *(const float4*)(cb + (size_t)m2 * (TT * DD) + 4 * j2); }

#define XSTORE(buf) { \
        _Float16* xb_ = &xs[(buf)][0][0][0]; \
        { int f = 4 * j0; float4 v = xr0; \
          xb_[((f+0)/6)*128 + m0*8 + ((f+0)%6)] = (_Float16)v.x; \
          xb_[((f+1)/6)*128 + m0*8 + ((f+1)%6)] = (_Float16)v.y; \
          xb_[((f+2)/6)*128 + m0*8 + ((f+2)%6)] = (_Float16)v.z; \
          xb_[((f+3)/6)*128 + m0*8 + ((f+3)%6)] = (_Float16)v.w; } \
        { int f = 4 * j1; float4 v = xr1; \
          xb_[((f+0)/6)*128 + m1*8 + ((f+0)%6)] = (_Float16)v.x; \
          xb_[((f+1)/6)*128 + m1*8 + ((f+1)%6)] = (_Float16)v.y; \
          xb_[((f+2)/6)*128 + m1*8 + ((f+2)%6)] = (_Float16)v.z; \
          xb_[((f+3)/6)*128 + m1*8 + ((f+3)%6)] = (_Float16)v.w; } \
        { int f = 4 * j2; float4 v = xr2; \
          xb_[((f+0)/6)*128 + m2*8 + ((f+0)%6)] = (_Float16)v.x; \
          xb_[((f+1)/6)*128 + m2*8 + ((f+1)%6)] = (_Float16)v.y; \
          xb_[((f+2)/6)*128 + m2*8 + ((f+2)%6)] = (_Float16)v.z; \
          xb_[((f+3)/6)*128 + m2*8 + ((f+3)%6)] = (_Float16)v.w; } }

    XLOAD(0)
    XSTORE(0)

    float cc0 = 0.f, cc1 = 0.f, cc2 = 0.f, cc3 = 0.f;   // c, PRE-SCALED by -2*log2e
    float hL0 = 0.f, hL1 = 0.f, hL2 = 0.f, hL3 = 0.f;   // fp32 h1 (LN epilogue)
    half8 AaN = {0,0,0,0,0,0,0,0};    // L1: prefetched h0 frag
    half8 AbN = {0,0,0,0,0,0,0,0};    // L0: prefetched x frag
    const f32x4 ZACC = {0.f, 0.f, 0.f, 0.f};

    __syncthreads();

    // initial x frag for s=0 (q>=1 lanes read x data their zero B-side ignores)
    AbN = *(const half8*)&xs[0][0][n][0];

    // reg-frag MFMA first (independent of the post-barrier ds_read)
#define GATE_L0(p) \
    f32x4 acc##p = MFMA_F16(AbN, Bb##p, ZACC); \
    acc##p = MFMA_F16(Aa, Ba##p, acc##p);
#define GATE_L1(p) \
    f32x4 acc##p = MFMA_F16(AaN, Ba##p, ZACC); \
    acc##p = MFMA_F16(Ab, Bb##p, acc##p);

    // rcp-merged update. A=K0*e0, F=K1*e1, B=K2*e2, O=K3*e3.
#define UPD(r, IS_L1, WS) { \
        float e0 = __builtin_amdgcn_exp2f(acc0[r]); \
        float e1 = __builtin_amdgcn_exp2f(acc1[r]); \
        float e2 = __builtin_amdgcn_exp2f(acc2[r]); \
        float e3 = __builtin_amdgcn_exp2f(acc3[r]); \
        float pA = fmaf(K0, e0, 1.0f); \
        float pF = fmaf(K1, e1, 1.0f); \
        float pB = fmaf(K2, e2, 1.0f); \
        float pO = fmaf(K3, e3, 1.0f); \
        float Qh = fmaf(K2c, e2, -L2E2); \
        float P  = pA * pB; \
        float R  = __builtin_amdgcn_rcpf(P * pF); \
        float nm = fmaf(cc##r, P, Qh * pF); \
        cc##r = nm * R; \
        float ec = __builtin_amdgcn_exp2f(cc##r); \
        float R2 = __builtin_amdgcn_rcpf(pO * (1.0f + ec)); \
        float h_ = (1.0f - ec) * R2; \
        if (IS_L1) { hL##r = h_; h1r[WS][4 * q + r][u] = (_Float16)h_; } \
        else       {             h0r[WS][4 * q + r][u] = (_Float16)h_; } }

    // Body J (s = s0+J), compile-time slots. XLOAD/XSTORE OUTSIDE the
    // role branch (cooperative). XSTORE at s%32==30 so the AbN prefetch
    // (end of body, reads xs slot for s+1) always sees >=1-barrier-old data.
#define BODY(J, S) { \
        if ((J) == 0 && ((S) & (CH - 1)) == 0 && (S) < TT - CH) { XLOAD(((S) >> 5) + 1) } \
        if (L) { \
            if ((S) >= 2 && (S) < TT + 2) { \
                half8 Ab = *(const half8*)&h1r[((J) + 1) & 1][n][8 * q]; \
                GATE_L1(0) GATE_L1(1) GATE_L1(2) GATE_L1(3) \
                UPD(0, 1, (J) & 1) UPD(1, 1, (J) & 1) \
                UPD(2, 1, (J) & 1) UPD(3, 1, (J) & 1) \
            } \
            AaN = *(const half8*)&h0r[((J) + 3) & 3][n][8 * q]; \
        } else { \
            if ((S) < TT) { \
                half8 Aa = *(const half8*)&h0r[((J) + 3) & 3][n][8 * q]; \
                GATE_L0(0) GATE_L0(1) GATE_L0(2) GATE_L0(3) \
                UPD(0, 0, (J) & 3) UPD(1, 0, (J) & 3) \
                UPD(2, 0, (J) & 3) UPD(3, 0, (J) & 3) \
            } \
            { const int sn = ((S) + 1 < TT) ? (S) + 1 : (S); \
              AbN = *(const half8*)&xs[(sn >> 5) & 1][sn & (CH - 1)][n][0]; } \
        } \
        if ((J) == 2 && (((S) & (CH - 1)) == 30) && (S) < TT - 2) { XSTORE((((S) >> 5) + 1) & 1) } \
        __syncthreads(); }

    #pragma unroll 1
    for (int s0 = 0; s0 < 516; s0 += 4) {
        BODY(0, s0)
        BODY(1, s0 + 1)
        BODY(2, s0 + 2)
        BODY(3, s0 + 3)
    }

    // ---------------- LayerNorm epilogue ----------------
    if (L) {
        ln_s[4 * q + 0][u] = hL0;
        ln_s[4 * q + 1][u] = hL1;
        ln_s[4 * q + 2][u] = hL2;
        ln_s[4 * q + 3][u] = hL3;
    }
    __syncthreads();

    if (tid < 16) {
        const int m = tid;
        float s = 0.f, s2 = 0.f;
        #pragma unroll
        for (int k = 0; k < HD; ++k) {
            float v = ln_s[m][k];
            s += v; s2 += v * v;
        }
        float mu  = s * (1.0f / HD);
        float var = s2 * (1.0f / HD) - mu * mu;
        float rr  = rsqrtf(var + EPSL);
        float* op = out + (size_t)(b0 + m) * HD;
        #pragma unroll
        for (int k = 0; k < HD; ++k)
            op[k] = (ln_s[m][k] - mu) * rr * gamma[k] + beta[k];
    }
}

extern "C" void kernel_launch(void* const* d_in, const int* in_sizes, int n_in,
                              void* d_out, int out_size, void* d_ws, size_t ws_size,
                              hipStream_t stream) {
    const float* x     = (const float*)d_in[0];
    const float* W_ih0 = (const float*)d_in[1];
    const float* W_hh0 = (const float*)d_in[2];
    const float* b_ih0 = (const float*)d_in[3];
    const float* b_hh0 = (const float*)d_in[4];
    const float* W_ih1 = (const float*)d_in[5];
    const float* W_hh1 = (const float*)d_in[6];
    const float* b_ih1 = (const float*)d_in[7];
    const float* b_hh1 = (const float*)d_in[8];
    const float* gamma = (const float*)d_in[9];
    const float* beta  = (const float*)d_in[10];
    float* out = (float*)d_out;

    const int B = in_sizes[0] / (TT * DD);   // 4096
    lstm2_pipe<<<B / 16, 256, 0, stream>>>(x, W_ih0, W_hh0, b_ih0, b_hh0,
                                           W_ih1, W_hh1, b_ih1, b_hh1,
                                           gamma, beta, out);
}

// Round 10
// 305.162 us; speedup vs baseline: 1.8356x; 1.0058x over previous
//
#include <hip/hip_runtime.h>

#define TT   512
#define DD   6
#define HD   32
#define CH   32          // x-staging chunk (timesteps)
#define EPSL 1e-5f
#define L2E  1.44269504f
#define L2E2 2.88539008f

typedef _Float16 half8 __attribute__((ext_vector_type(8)));
typedef __attribute__((ext_vector_type(4))) float f32x4;

#define MFMA_F16(a, b, c) __builtin_amdgcn_mfma_f32_16x16x32_f16((a), (b), (c), 0, 0, 0)

// ====================================================================
// R10 = R9 with ALL LDS reads hoisted to the TOP of each body.
// R9 lesson: prefetches placed after UPD just moved the ~120cy ds_read
// latency into the pre-barrier lgkmcnt(0) drain (neutral). Issued at the
// top of the body — before the 8 MFMAs and ~340cy UPD block — their
// latency is fully hidden and lgkm is drained long before the barrier.
// Reads are unconditional (rings zero-initialized; inactive-step reads
// harmless) so they sit outside the active-if and can't be sunk.
// Structure audit (R9): work = exactly 1024 waves = 1 wave/SIMD; all
// remappings either idle CUs, break lane-local 4-gate UPD, or double
// per-wave trans. Remaining gap is schedule slack only.
// ====================================================================
__global__ __launch_bounds__(256, 1) void lstm2_pipe(
    const float* __restrict__ x,      // (B,512,6)
    const float* __restrict__ W_ih0,  // (128,6)
    const float* __restrict__ W_hh0,  // (128,32)
    const float* __restrict__ b_ih0,
    const float* __restrict__ b_hh0,
    const float* __restrict__ W_ih1,  // (128,32)
    const float* __restrict__ W_hh1,  // (128,32)
    const float* __restrict__ b_ih1,
    const float* __restrict__ b_hh1,
    const float* __restrict__ gamma,
    const float* __restrict__ beta,
    float* __restrict__ out)          // (B,32)
{
    const int tid = threadIdx.x;
    const int w   = tid >> 6;
    const int L   = w >> 1;        // 0: layer-0 role, 1: layer-1 role
    const int uh  = w & 1;         // unit half
    const int ln  = tid & 63;
    const int q   = ln >> 4;
    const int n   = ln & 15;
    const int u   = 16 * uh + n;
    const int b0  = blockIdx.x << 4;

    __shared__ __align__(16) _Float16 h0r[4][16][40];
    __shared__ __align__(16) _Float16 h1r[2][16][40];
    __shared__ __align__(16) _Float16 xs[2][CH][16][8];
    __shared__ float ln_s[16][33];

    {   // zero rings and xs pads
        unsigned* p0 = (unsigned*)&h0r[0][0][0];
        for (int i = tid; i < (int)(sizeof(h0r) / 4); i += 256) p0[i] = 0u;
        unsigned* p1 = (unsigned*)&h1r[0][0][0];
        for (int i = tid; i < (int)(sizeof(h1r) / 4); i += 256) p1[i] = 0u;
        unsigned* p2 = (unsigned*)&xs[0][0][0][0];
        for (int i = tid; i < (int)(sizeof(xs) / 4); i += 256) p2[i] = 0u;
    }
    __syncthreads();   // xs fully zeroed before the prologue XSTORE(0)

    // ---------------- weight B-frags (fp16, pre-scaled) ----------------
    const float* Wa = L ? W_ih1 : W_hh0;
    const float* bi = L ? b_ih1 : b_ih0;
    const float* bh = L ? b_hh1 : b_hh0;

#define SETUP(p, SC) \
    half8 Ba##p, Bb##p; float K##p; { \
        const int g = 32 * (p) + u; \
        const float4* r4 = (const float4*)(Wa + g * 32 + 8 * q); \
        float4 va = r4[0], vb = r4[1]; \
        Ba##p = half8{(_Float16)(SC * va.x), (_Float16)(SC * va.y), \
                      (_Float16)(SC * va.z), (_Float16)(SC * va.w), \
                      (_Float16)(SC * vb.x), (_Float16)(SC * vb.y), \
                      (_Float16)(SC * vb.z), (_Float16)(SC * vb.w)}; \
        Bb##p = half8{0, 0, 0, 0, 0, 0, 0, 0}; \
        if (L) { \
            const float4* s4 = (const float4*)(W_hh1 + g * 32 + 8 * q); \
            float4 sa = s4[0], sb = s4[1]; \
            Bb##p = half8{(_Float16)(SC * sa.x), (_Float16)(SC * sa.y), \
                          (_Float16)(SC * sa.z), (_Float16)(SC * sa.w), \
                          (_Float16)(SC * sb.x), (_Float16)(SC * sb.y), \
                          (_Float16)(SC * sb.z), (_Float16)(SC * sb.w)}; \
        } else if (q == 0) { \
            const float* xw = W_ih0 + g * 6; \
            Bb##p[0] = (_Float16)(SC * xw[0]); Bb##p[1] = (_Float16)(SC * xw[1]); \
            Bb##p[2] = (_Float16)(SC * xw[2]); Bb##p[3] = (_Float16)(SC * xw[3]); \
            Bb##p[4] = (_Float16)(SC * xw[4]); Bb##p[5] = (_Float16)(SC * xw[5]); \
        } \
        K##p = __builtin_amdgcn_exp2f(SC * (bi[g] + bh[g])); \
    }
    SETUP(0, -L2E) SETUP(1, -L2E) SETUP(2, -L2E2) SETUP(3, -L2E)
    const float K2c = L2E2 * K2;

    // ---------------- x chunk machinery (cooperative, all 256 threads) ----
    const int m0 = (tid       ) / 48, j0 = (tid       ) % 48;
    const int m1 = (tid + 256 ) / 48, j1 = (tid + 256 ) % 48;
    const int m2 = (tid + 512 ) / 48, j2 = (tid + 512 ) % 48;
    float4 xr0, xr1, xr2;

#define XLOAD(ch) { \
        const float* cb = x + (size_t)b0 * (TT * DD) + (ch) * (CH * DD); \
        xr0 = *(const float4*)(cb + (size_t)m0 * (TT * DD) + 4 * j0); \
        xr1 = *(const float4*)(cb + (size_t)m1 * (TT * DD) + 4 * j1); \
        xr2 = *(const float4*)(cb + (size_t)m2 * (TT * DD) + 4 * j2); }

#define XSTORE(buf) { \
        _Float16* xb_ = &xs[(buf)][0][0][0]; \
        { int f = 4 * j0; float4 v = xr0; \
          xb_[((f+0)/6)*128 + m0*8 + ((f+0)%6)] = (_Float16)v.x; \
          xb_[((f+1)/6)*128 + m0*8 + ((f+1)%6)] = (_Float16)v.y; \
          xb_[((f+2)/6)*128 + m0*8 + ((f+2)%6)] = (_Float16)v.z; \
          xb_[((f+3)/6)*128 + m0*8 + ((f+3)%6)] = (_Float16)v.w; } \
        { int f = 4 * j1; float4 v = xr1; \
          xb_[((f+0)/6)*128 + m1*8 + ((f+0)%6)] = (_Float16)v.x; \
          xb_[((f+1)/6)*128 + m1*8 + ((f+1)%6)] = (_Float16)v.y; \
          xb_[((f+2)/6)*128 + m1*8 + ((f+2)%6)] = (_Float16)v.z; \
          xb_[((f+3)/6)*128 + m1*8 + ((f+3)%6)] = (_Float16)v.w; } \
        { int f = 4 * j2; float4 v = xr2; \
          xb_[((f+0)/6)*128 + m2*8 + ((f+0)%6)] = (_Float16)v.x; \
          xb_[((f+1)/6)*128 + m2*8 + ((f+1)%6)] = (_Float16)v.y; \
          xb_[((f+2)/6)*128 + m2*8 + ((f+2)%6)] = (_Float16)v.z; \
          xb_[((f+3)/6)*128 + m2*8 + ((f+3)%6)] = (_Float16)v.w; } }

    XLOAD(0)
    XSTORE(0)

    float cc0 = 0.f, cc1 = 0.f, cc2 = 0.f, cc3 = 0.f;   // c, PRE-SCALED by -2*log2e
    float hL0 = 0.f, hL1 = 0.f, hL2 = 0.f, hL3 = 0.f;   // fp32 h1 (LN epilogue)
    half8 AaN = {0,0,0,0,0,0,0,0};    // L1: prefetched h0 frag
    half8 AbN = {0,0,0,0,0,0,0,0};    // L0: prefetched x frag
    const f32x4 ZACC = {0.f, 0.f, 0.f, 0.f};

    __syncthreads();

    // initial x frag for s=0 (q>=1 lanes read x data their zero B-side ignores)
    AbN = *(const half8*)&xs[0][0][n][0];

    // reg-frag MFMA first (independent of the post-barrier ds_read)
#define GATE_L0(p) \
    f32x4 acc##p = MFMA_F16(AbN, Bb##p, ZACC); \
    acc##p = MFMA_F16(Aa, Ba##p, acc##p);
#define GATE_L1(p) \
    f32x4 acc##p = MFMA_F16(AaN, Ba##p, ZACC); \
    acc##p = MFMA_F16(Ab, Bb##p, acc##p);

    // rcp-merged update. A=K0*e0, F=K1*e1, B=K2*e2, O=K3*e3.
#define UPD(r, IS_L1, WS) { \
        float e0 = __builtin_amdgcn_exp2f(acc0[r]); \
        float e1 = __builtin_amdgcn_exp2f(acc1[r]); \
        float e2 = __builtin_amdgcn_exp2f(acc2[r]); \
        float e3 = __builtin_amdgcn_exp2f(acc3[r]); \
        float pA = fmaf(K0, e0, 1.0f); \
        float pF = fmaf(K1, e1, 1.0f); \
        float pB = fmaf(K2, e2, 1.0f); \
        float pO = fmaf(K3, e3, 1.0f); \
        float Qh = fmaf(K2c, e2, -L2E2); \
        float P  = pA * pB; \
        float R  = __builtin_amdgcn_rcpf(P * pF); \
        float nm = fmaf(cc##r, P, Qh * pF); \
        cc##r = nm * R; \
        float ec = __builtin_amdgcn_exp2f(cc##r); \
        float R2 = __builtin_amdgcn_rcpf(pO * (1.0f + ec)); \
        float h_ = (1.0f - ec) * R2; \
        if (IS_L1) { hL##r = h_; h1r[WS][4 * q + r][u] = (_Float16)h_; } \
        else       {             h0r[WS][4 * q + r][u] = (_Float16)h_; } }

    // Body J (s = s0+J), compile-time slots. ALL LDS reads (current frags
    // AND next-iter prefetches) issue at the TOP, unconditionally, so the
    // ~120cy latency hides under the 8 MFMAs + ~340cy UPD that follow.
#define BODY(J, S) { \
        if ((J) == 0 && ((S) & (CH - 1)) == 0 && (S) < TT - CH) { XLOAD(((S) >> 5) + 1) } \
        if (L) { \
            half8 Ab      = *(const half8*)&h1r[((J) + 1) & 1][n][8 * q]; \
            half8 AaN_nxt = *(const half8*)&h0r[((J) + 3) & 3][n][8 * q]; \
            if ((S) >= 2 && (S) < TT + 2) { \
                GATE_L1(0) GATE_L1(1) GATE_L1(2) GATE_L1(3) \
                UPD(0, 1, (J) & 1) UPD(1, 1, (J) & 1) \
                UPD(2, 1, (J) & 1) UPD(3, 1, (J) & 1) \
            } \
            AaN = AaN_nxt; \
        } else { \
            half8 Aa      = *(const half8*)&h0r[((J) + 3) & 3][n][8 * q]; \
            const int sn  = ((S) + 1 < TT) ? (S) + 1 : (S); \
            half8 AbN_nxt = *(const half8*)&xs[(sn >> 5) & 1][sn & (CH - 1)][n][0]; \
            if ((S) < TT) { \
                GATE_L0(0) GATE_L0(1) GATE_L0(2) GATE_L0(3) \
                UPD(0, 0, (J) & 3) UPD(1, 0, (J) & 3) \
                UPD(2, 0, (J) & 3) UPD(3, 0, (J) & 3) \
            } \
            AbN = AbN_nxt; \
        } \
        if ((J) == 2 && (((S) & (CH - 1)) == 30) && (S) < TT - 2) { XSTORE((((S) >> 5) + 1) & 1) } \
        __syncthreads(); }

    #pragma unroll 1
    for (int s0 = 0; s0 < 516; s0 += 4) {
        BODY(0, s0)
        BODY(1, s0 + 1)
        BODY(2, s0 + 2)
        BODY(3, s0 + 3)
    }

    // ---------------- LayerNorm epilogue ----------------
    if (L) {
        ln_s[4 * q + 0][u] = hL0;
        ln_s[4 * q + 1][u] = hL1;
        ln_s[4 * q + 2][u] = hL2;
        ln_s[4 * q + 3][u] = hL3;
    }
    __syncthreads();

    if (tid < 16) {
        const int m = tid;
        float s = 0.f, s2 = 0.f;
        #pragma unroll
        for (int k = 0; k < HD; ++k) {
            float v = ln_s[m][k];
            s += v; s2 += v * v;
        }
        float mu  = s * (1.0f / HD);
        float var = s2 * (1.0f / HD) - mu * mu;
        float rr  = rsqrtf(var + EPSL);
        float* op = out + (size_t)(b0 + m) * HD;
        #pragma unroll
        for (int k = 0; k < HD; ++k)
            op[k] = (ln_s[m][k] - mu) * rr * gamma[k] + beta[k];
    }
}

extern "C" void kernel_launch(void* const* d_in, const int* in_sizes, int n_in,
                              void* d_out, int out_size, void* d_ws, size_t ws_size,
                              hipStream_t stream) {
    const float* x     = (const float*)d_in[0];
    const float* W_ih0 = (const float*)d_in[1];
    const float* W_hh0 = (const float*)d_in[2];
    const float* b_ih0 = (const float*)d_in[3];
    const float* b_hh0 = (const float*)d_in[4];
    const float* W_ih1 = (const float*)d_in[5];
    const float* W_hh1 = (const float*)d_in[6];
    const float* b_ih1 = (const float*)d_in[7];
    const float* b_hh1 = (const float*)d_in[8];
    const float* gamma = (const float*)d_in[9];
    const float* beta  = (const float*)d_in[10];
    float* out = (float*)d_out;

    const int B = in_sizes[0] / (TT * DD);   // 4096
    lstm2_pipe<<<B / 16, 256, 0, stream>>>(x, W_ih0, W_hh0, b_ih0, b_hh0,
                                           W_ih1, W_hh1, b_ih1, b_hh1,
                                           gamma, beta, out);
}